// Round 6
// baseline (144.926 us; speedup 1.0000x reference)
//
#include <hip/hip_runtime.h>
#include <math.h>

#define N_ 2
#define L_ 2048
#define S_ 2048
#define H_ 8
#define D_ 64

#define BLK_L 256        // l-rows per block (4 waves x 64 rows)
#define BS 64            // s-rows per K tile (4 fragment groups of 16)
#define SSPLIT 8         // z-split over S

typedef __attribute__((ext_vector_type(8))) short short8;
typedef __attribute__((ext_vector_type(4))) float floatx4;

__device__ __forceinline__ float feat(float x) {
    // elu(x)+1 = x>0 ? x+1 : exp(x)
    return x > 0.0f ? x + 1.0f : __expf(x);
}
__device__ __forceinline__ short f2bf(float x) {
    unsigned u = __float_as_uint(x);
    unsigned r = (u + 0x7fffu + ((u >> 16) & 1u)) >> 16;   // round-nearest-even
    return (short)r;
}
__device__ __forceinline__ float bf2f(short h) {
    return __uint_as_float(((unsigned)(unsigned short)h) << 16);
}

// -------------------------------------------------------------------------
// K-plane layout: FRAGMENT-LINEAR. Per (nh), per 16-row s-group g:
//   8 slots (d-chunk c = d/8), each [16 rows][8 shorts].
//   short offset(s, c) = nh*S*D + (s>>4)*1024 + (c>>2)*512 + ((c&3)*16 + (s&15))*8
// A wave's MFMA B-fragment (lane quad=lane>>4 reads chunk quad / quad+4,
// row l16=lane&15) is then the CONTIGUOUS 1 KB block at group_base (+512),
// address = base + lane*16B -> perfectly coalesced L2-resident load.
// No LDS staging, no barriers, no swizzle needed in the consumer.
// -------------------------------------------------------------------------

// featk: featurize K once -> bf16 hi/lo fragment-linear planes. Fuses the
// per-block Ksum partial reduce (plain stores -> no memset, no atomics).
__global__ __launch_bounds__(256) void featk_kernel(
        const float* __restrict__ K, const float* __restrict__ kvmask,
        short* __restrict__ Khi, short* __restrict__ Klo,
        float* __restrict__ Kpart) {
    __shared__ float sm[64][68];           // +4 pad
    __shared__ float sm2[256];
    int nh = blockIdx.x;                   // 16
    int z  = blockIdx.y;                   // 32 chunks of 64 s-rows
    int n = nh >> 3, h = nh & 7;
    int t = threadIdx.x;
    int srow = t >> 2, g = t & 3;          // thread covers d in [g*16, g*16+16)
    int s = z * 64 + srow;

    float km = kvmask[n * S_ + s];
    const float* kp = K + (((size_t)n * S_ + s) * H_ + h) * D_ + g * 16;
    float fv[16];
    #pragma unroll
    for (int j = 0; j < 4; ++j) {
        float4 v = *(const float4*)(kp + j * 4);
        fv[4 * j + 0] = feat(v.x) * km;
        fv[4 * j + 1] = feat(v.y) * km;
        fv[4 * j + 2] = feat(v.z) * km;
        fv[4 * j + 3] = feat(v.w) * km;
    }
    short8 h0, h1, l0, l1;
    #pragma unroll
    for (int j = 0; j < 8; ++j) {
        short hb = f2bf(fv[j]);
        h0[j] = hb;  l0[j] = f2bf(fv[j] - bf2f(hb));
        short hb2 = f2bf(fv[8 + j]);
        h1[j] = hb2; l1[j] = f2bf(fv[8 + j] - bf2f(hb2));
    }
    // fragment-linear offsets for chunks c0=2g, c1=2g+1
    size_t pbase = (size_t)nh * (S_ * D_) + (size_t)(s >> 4) * 1024;
    int c0 = 2 * g, c1 = 2 * g + 1;
    size_t o0 = pbase + ((c0 >> 2) * 512) + (((c0 & 3) * 16 + (s & 15)) * 8);
    size_t o1 = pbase + ((c1 >> 2) * 512) + (((c1 & 3) * 16 + (s & 15)) * 8);
    *(short8*)(Khi + o0) = h0;
    *(short8*)(Khi + o1) = h1;
    *(short8*)(Klo + o0) = l0;
    *(short8*)(Klo + o1) = l1;

    // ---- Ksum partial: parallel 16-row partials, 4-way combine, plain store
    #pragma unroll
    for (int j2 = 0; j2 < 4; ++j2)
        *(float4*)&sm[srow][g * 16 + 4 * j2] =
            make_float4(fv[4 * j2], fv[4 * j2 + 1], fv[4 * j2 + 2], fv[4 * j2 + 3]);
    __syncthreads();
    {
        int d = t & 63, grp = t >> 6;
        float part = 0.f;
        #pragma unroll
        for (int k = 0; k < 16; ++k) part += sm[grp * 16 + k][d];
        sm2[t] = part;
    }
    __syncthreads();
    if (t < 64) {
        float tot = sm2[t] + sm2[t + 64] + sm2[t + 128] + sm2[t + 192];
        Kpart[(nh * 32 + z) * 64 + t] = tot;
    }
}

// -------------------------------------------------------------------------
// rowmax: 16x16x32 bf16 MFMA (3-product hi/lo), B-fragments read DIRECTLY
// from the fragment-linear L2-resident planes (coalesced 1KB/wave loads).
// No LDS, no barriers -> pure dataflow, compiler-pipelined. Round-5 LDS
// version was LDS-read-throughput-bound (4x B re-read amplification).
// Designated blocks fold Kpart -> Ksum in the prologue.
// -------------------------------------------------------------------------
__global__ __launch_bounds__(256) void rowmax_mfma(
        const float* __restrict__ Q, const short* __restrict__ Khi,
        const short* __restrict__ Klo, const float* __restrict__ qmask,
        const float* __restrict__ Kpart, float* __restrict__ Ksum,
        float* __restrict__ rmax_part) {
    // Bijective XCD swizzle: 1024 wgs, 128 per XCD; the 8 lblocks sharing a
    // (nh,z) K-slice are nid-consecutive -> same XCD chunk -> L2-shared.
    int flat = blockIdx.x + (blockIdx.y << 3) + (blockIdx.z << 7);
    int nid  = ((flat & 7) << 7) | (flat >> 3);
    int bx = nid & 7;            // lblock index
    int nh = (nid >> 3) & 15;    // (n,h)
    int z  = nid >> 7;           // s-split, 0..7

    int n = nh >> 3, h = nh & 7;
    int t = threadIdx.x;
    int w = t >> 6, lane = t & 63;
    int quad = lane >> 4, l16 = lane & 15;
    int lblock = bx * BLK_L;

    // ---- designated blocks fold Ksum (overlaps with other blocks' work)
    if (bx == 0 && z == 0 && t < 64) {
        float s = 0.f;
        #pragma unroll
        for (int zz = 0; zz < 32; ++zz)
            s += Kpart[(nh * 32 + zz) * 64 + t];
        Ksum[nh * 64 + t] = s;
    }

    // ---- A fragments: featurized Q, bf16 hi/lo split, in registers ----
    // A-frag layout (16x16x32): m = lane&15, k = quad*8 + j
    short8 Ah[4][2], Al[4][2];
    #pragma unroll
    for (int lsub = 0; lsub < 4; ++lsub) {
        int lrow = lblock + w * 64 + lsub * 16 + l16;
        float qm = qmask[n * L_ + lrow];
        const float* qp = Q + (((size_t)n * L_ + lrow) * H_ + h) * D_ + quad * 8;
        #pragma unroll
        for (int ks = 0; ks < 2; ++ks) {
            float4 v0 = *(const float4*)(qp + ks * 32);
            float4 v1 = *(const float4*)(qp + ks * 32 + 4);
            float fv[8];
            fv[0] = feat(v0.x) * qm; fv[1] = feat(v0.y) * qm;
            fv[2] = feat(v0.z) * qm; fv[3] = feat(v0.w) * qm;
            fv[4] = feat(v1.x) * qm; fv[5] = feat(v1.y) * qm;
            fv[6] = feat(v1.z) * qm; fv[7] = feat(v1.w) * qm;
            short8 hi, lo;
            #pragma unroll
            for (int j = 0; j < 8; ++j) {
                short hb = f2bf(fv[j]);
                hi[j] = hb;
                lo[j] = f2bf(fv[j] - bf2f(hb));
            }
            Ah[lsub][ks] = hi;
            Al[lsub][ks] = lo;
        }
    }

    // slice base: z covers S/SSPLIT = 256 s-rows = 16 groups of 1024 shorts
    const short* ph = Khi + (size_t)nh * (S_ * D_) + (size_t)z * (S_ / SSPLIT) * D_;
    const short* pl = Klo + (size_t)nh * (S_ * D_) + (size_t)z * (S_ / SSPLIT) * D_;

    float rmax[4][4];
    #pragma unroll
    for (int i = 0; i < 4; ++i)
        #pragma unroll
        for (int r = 0; r < 4; ++r) rmax[i][r] = 0.f;   // dots >= 0

    const int tiles = S_ / SSPLIT / BS;    // 4 (each tile = 4 groups)
    for (int tile = 0; tile < tiles; ++tile) {
        #pragma unroll
        for (int ssub = 0; ssub < 4; ++ssub) {
            // group gg = tile*4 + ssub; B-frag = contiguous 1KB at gg*1024
            const short* gbh = ph + ((tile * 4 + ssub) * 1024) + (lane << 3);
            const short* gbl = pl + ((tile * 4 + ssub) * 1024) + (lane << 3);
            short8 Bh0 = *(const short8*)(gbh);
            short8 Bh1 = *(const short8*)(gbh + 512);
            short8 Bl0 = *(const short8*)(gbl);
            short8 Bl1 = *(const short8*)(gbl + 512);
            #pragma unroll
            for (int lsub = 0; lsub < 4; ++lsub) {
                floatx4 acc = {0.f, 0.f, 0.f, 0.f};
                acc = __builtin_amdgcn_mfma_f32_16x16x32_bf16(Ah[lsub][0], Bh0, acc, 0, 0, 0);
                acc = __builtin_amdgcn_mfma_f32_16x16x32_bf16(Ah[lsub][1], Bh1, acc, 0, 0, 0);
                acc = __builtin_amdgcn_mfma_f32_16x16x32_bf16(Ah[lsub][0], Bl0, acc, 0, 0, 0);
                acc = __builtin_amdgcn_mfma_f32_16x16x32_bf16(Ah[lsub][1], Bl1, acc, 0, 0, 0);
                acc = __builtin_amdgcn_mfma_f32_16x16x32_bf16(Al[lsub][0], Bh0, acc, 0, 0, 0);
                acc = __builtin_amdgcn_mfma_f32_16x16x32_bf16(Al[lsub][1], Bh1, acc, 0, 0, 0);
                #pragma unroll
                for (int r = 0; r < 4; ++r)
                    rmax[lsub][r] = fmaxf(rmax[lsub][r], acc[r]);
            }
        }
    }

    // ---- epilogue: reduce rowmax across the 16 column-lanes, plain store ----
    // C/D layout: col(s) = lane&15, row(l) = quad*4 + r
    #pragma unroll
    for (int lsub = 0; lsub < 4; ++lsub)
        #pragma unroll
        for (int r = 0; r < 4; ++r) {
            float m = rmax[lsub][r];
            m = fmaxf(m, __shfl_xor(m, 1, 64));
            m = fmaxf(m, __shfl_xor(m, 2, 64));
            m = fmaxf(m, __shfl_xor(m, 4, 64));
            m = fmaxf(m, __shfl_xor(m, 8, 64));
            if (l16 == 0) {
                int l = lblock + w * 64 + lsub * 16 + quad * 4 + r;
                rmax_part[((size_t)(z * 16 + nh)) * L_ + l] = m;
            }
        }
}

// -------------------------------------------------------------------------
// finalize: float4 per thread; 16-lane row reduction for the mean-dot;
// max over the 8 z rowmax partials; gate; masked output.
// -------------------------------------------------------------------------
__global__ __launch_bounds__(256) void finalize_kernel(
        const float* __restrict__ Q, const float* __restrict__ qmask,
        const float* __restrict__ Ksum, const float* __restrict__ rmax_part,
        const float* __restrict__ W, const float* __restrict__ b,
        float* __restrict__ out) {
    int t = threadIdx.x;
    int fid = blockIdx.x * 256 + t;        // float4 index
    int wid = fid >> 4;                    // (n,l,h) row id
    int sub = fid & 15;                    // 16B chunk within the 64-d row
    int n = wid / (L_ * H_);
    int lh = wid % (L_ * H_);
    int l = lh / H_, h = lh % H_;
    int nh = n * H_ + h;

    float4 q4 = ((const float4*)Q)[fid];
    float qm = qmask[n * L_ + l];
    float4 ks4 = ((const float4*)(Ksum + nh * 64))[sub];
    float p = feat(q4.x) * ks4.x + feat(q4.y) * ks4.y
            + feat(q4.z) * ks4.z + feat(q4.w) * ks4.w;
    p *= qm;
    p += __shfl_xor(p, 1, 64);
    p += __shfl_xor(p, 2, 64);
    p += __shfl_xor(p, 4, 64);
    p += __shfl_xor(p, 8, 64);             // sum across the row's 16 lanes
    float mean = p * (1.0f / S_);
    float mx = rmax_part[(size_t)nh * L_ + l];
    #pragma unroll
    for (int zz = 1; zz < SSPLIT; ++zz)
        mx = fmaxf(mx, rmax_part[((size_t)(zz * 16 + nh)) * L_ + l]);
    float zz2 = W[0] * mean + W[1] * mx + b[0];
    float g = 1.0f / (1.0f + __expf(-zz2));
    float4 o;
    o.x = q4.x * qm * g; o.y = q4.y * qm * g;
    o.z = q4.z * qm * g; o.w = q4.w * qm * g;
    ((float4*)out)[fid] = o;
}

extern "C" void kernel_launch(void* const* d_in, const int* in_sizes, int n_in,
                              void* d_out, int out_size, void* d_ws, size_t ws_size,
                              hipStream_t stream) {
    const float* Q      = (const float*)d_in[0];
    const float* K      = (const float*)d_in[1];
    // d_in[2] = values: masked in reference but unused downstream
    const float* qmask  = (const float*)d_in[3];
    const float* kvmask = (const float*)d_in[4];
    const float* W      = (const float*)d_in[5];
    const float* b      = (const float*)d_in[6];
    float* out = (float*)d_out;

    // workspace layout (floats), everything written before read, no init:
    float* Ksum      = (float*)d_ws;                     // 1024
    float* Kpart     = Ksum + 1024;                      // 16*32*64 = 32768
    float* rmax_part = Kpart + 32768;                    // 8*16*2048 = 262144
    short* Khi       = (short*)(rmax_part + 262144);     // 4 MB (16B-aligned)
    short* Klo       = Khi + (size_t)N_ * H_ * S_ * D_;  // 4 MB

    featk_kernel<<<dim3(N_ * H_, S_ / 64), 256, 0, stream>>>(K, kvmask, Khi, Klo, Kpart);
    rowmax_mfma<<<dim3(L_ / BLK_L, N_ * H_, SSPLIT), 256, 0, stream>>>(
        Q, Khi, Klo, qmask, Kpart, Ksum, rmax_part);
    finalize_kernel<<<dim3((N_ * L_ * H_ * D_ / 4) / 256), 256, 0, stream>>>(
        Q, qmask, Ksum, rmax_part, W, b, out);
}

// Round 7
// 110.545 us; speedup vs baseline: 1.3110x; 1.3110x over previous
//
#include <hip/hip_runtime.h>
#include <math.h>

#define N_ 2
#define L_ 2048
#define S_ 2048
#define H_ 8
#define D_ 64

#define BLK_L 256        // l-rows per block (4 waves x 64 rows)
#define BS 64            // s-rows per K tile
#define SSPLIT 4         // z-split over S

typedef __attribute__((ext_vector_type(8))) short short8;
typedef __attribute__((ext_vector_type(4))) float floatx4;

__device__ __forceinline__ float feat(float x) {
    // elu(x)+1 = x>0 ? x+1 : exp(x)
    return x > 0.0f ? x + 1.0f : __expf(x);
}
__device__ __forceinline__ short f2bf(float x) {
    unsigned u = __float_as_uint(x);
    unsigned r = (u + 0x7fffu + ((u >> 16) & 1u)) >> 16;   // round-nearest-even
    return (short)r;
}
__device__ __forceinline__ float bf2f(short h) {
    return __uint_as_float(((unsigned)(unsigned short)h) << 16);
}
__device__ __forceinline__ void gload_lds16(const void* g, void* l) {
    // 16B direct global->LDS DMA; LDS dest is wave-uniform base + lane*16
    __builtin_amdgcn_global_load_lds(
        (__attribute__((address_space(1))) void*)g,
        (__attribute__((address_space(3))) void*)l, 16, 0, 0);
}

// -------------------------------------------------------------------------
// featk: featurize K once -> bf16 hi/lo planes [n][h][s][64], slot-swizzled
// (16B slot c of row s stored at slot c ^ (s&7)) so a LINEAR global_load_lds
// copy yields a conflict-mitigated swizzled LDS tile. Writes per-block Ksum
// partials (plain stores -> no memset, no atomics).
// -------------------------------------------------------------------------
__global__ __launch_bounds__(256) void featk_kernel(
        const float* __restrict__ K, const float* __restrict__ kvmask,
        short* __restrict__ Khi, short* __restrict__ Klo,
        float* __restrict__ Kpart) {
    __shared__ float sm[64][68];           // +4 pad
    __shared__ float sm2[256];
    int nh = blockIdx.x;                   // 16
    int z  = blockIdx.y;                   // 32 chunks of 64 s-rows
    int n = nh >> 3, h = nh & 7;
    int t = threadIdx.x;
    int srow = t >> 2, g = t & 3;          // thread covers d in [g*16, g*16+16)
    int s = z * 64 + srow;

    float km = kvmask[n * S_ + s];
    const float* kp = K + (((size_t)n * S_ + s) * H_ + h) * D_ + g * 16;
    float fv[16];
    #pragma unroll
    for (int j = 0; j < 4; ++j) {
        float4 v = *(const float4*)(kp + j * 4);
        fv[4 * j + 0] = feat(v.x) * km;
        fv[4 * j + 1] = feat(v.y) * km;
        fv[4 * j + 2] = feat(v.z) * km;
        fv[4 * j + 3] = feat(v.w) * km;
    }
    short8 h0, h1, l0, l1;
    #pragma unroll
    for (int j = 0; j < 8; ++j) {
        short hb = f2bf(fv[j]);
        h0[j] = hb;  l0[j] = f2bf(fv[j] - bf2f(hb));
        short hb2 = f2bf(fv[8 + j]);
        h1[j] = hb2; l1[j] = f2bf(fv[8 + j] - bf2f(hb2));
    }
    size_t rowbase = ((size_t)nh * S_ + s) * (size_t)D_;   // shorts
    int rx = srow & 7;
    // chunks 2g and 2g+1, swizzled slot = chunk ^ (s&7)
    *(short8*)(Khi + rowbase + ((((2 * g)    ) ^ rx) << 3)) = h0;
    *(short8*)(Khi + rowbase + ((((2 * g) + 1) ^ rx) << 3)) = h1;
    *(short8*)(Klo + rowbase + ((((2 * g)    ) ^ rx) << 3)) = l0;
    *(short8*)(Klo + rowbase + ((((2 * g) + 1) ^ rx) << 3)) = l1;

    // ---- Ksum partial: parallel 16-row partials, 4-way combine, plain store
    #pragma unroll
    for (int j2 = 0; j2 < 4; ++j2)
        *(float4*)&sm[srow][g * 16 + 4 * j2] =
            make_float4(fv[4 * j2], fv[4 * j2 + 1], fv[4 * j2 + 2], fv[4 * j2 + 3]);
    __syncthreads();
    {
        int d = t & 63, grp = t >> 6;
        float part = 0.f;
        #pragma unroll
        for (int k = 0; k < 16; ++k) part += sm[grp * 16 + k][d];
        sm2[t] = part;
    }
    __syncthreads();
    if (t < 64) {
        float tot = sm2[t] + sm2[t + 64] + sm2[t + 128] + sm2[t + 192];
        Kpart[(nh * 32 + z) * 64 + t] = tot;
    }
}

// -------------------------------------------------------------------------
// rowmax: 16x16x32 bf16 MFMA (3-product hi/lo) over prefeaturized K planes.
// 4 waves / 256 threads — register-light (no spill). Double-buffered
// global_load_lds staging (DMA prefetch = the latency hiding; the round-6
// L2-direct variant was latency-bound at 10% occupancy: 63 us vs ~6 us).
// One barrier per tile. Designated blocks fold Kpart -> Ksum in the
// prologue. Per-z rowmax partials stored plain (no atomics, no init).
// -------------------------------------------------------------------------
__global__ __launch_bounds__(256) void rowmax_mfma(
        const float* __restrict__ Q, const short* __restrict__ Khi,
        const short* __restrict__ Klo, const float* __restrict__ qmask,
        const float* __restrict__ Kpart, float* __restrict__ Ksum,
        float* __restrict__ rmax_part) {
    __shared__ __align__(16) char lds[2][16384];   // [dbuf][hi 8KB | lo 8KB]

    // Bijective XCD swizzle: the 8 lblocks sharing a (nh,z) K-slice map to
    // consecutive nid -> same XCD chunk. 512 wgs, 64 per XCD.
    int flat = blockIdx.x + (blockIdx.y << 3) + (blockIdx.z << 7);
    int nid  = ((flat & 7) << 6) | (flat >> 3);
    int bx = nid & 7;            // lblock index
    int nh = (nid >> 3) & 15;    // (n,h)
    int z  = nid >> 7;           // s-split

    int n = nh >> 3, h = nh & 7;
    int t = threadIdx.x;
    int w = t >> 6, lane = t & 63;
    int quad = lane >> 4, l16 = lane & 15;
    int lblock = bx * BLK_L;

    const char* gKh = (const char*)Khi + ((size_t)nh * S_ + (size_t)z * (S_ / SSPLIT)) * 128;
    const char* gKl = (const char*)Klo + ((size_t)nh * S_ + (size_t)z * (S_ / SSPLIT)) * 128;
    int sidx = w << 2;   // this wave's 4 copy-chunk ids (waves 0-1: hi, 2-3: lo)

    auto stage = [&](int tile, int db) {
        #pragma unroll
        for (int c = 0; c < 4; ++c) {
            int idx = sidx | c;                              // 0..15
            const char* src = (idx < 8 ? gKh : gKl)
                              + tile * 8192 + ((idx & 7) << 10) + (lane << 4);
            gload_lds16(src, &lds[db][idx << 10]);
        }
    };

    stage(0, 0);   // tile 0 in flight while we fold Ksum + featurize Q

    // ---- designated blocks fold Ksum (hidden under stage(0) + Q prologue)
    if (bx == 0 && z == 0 && t < 64) {
        float s = 0.f;
        #pragma unroll
        for (int zz = 0; zz < 32; ++zz)
            s += Kpart[(nh * 32 + zz) * 64 + t];
        Ksum[nh * 64 + t] = s;
    }

    // ---- A fragments: featurized Q, bf16 hi/lo split, in registers ----
    // A-frag layout (16x16x32): m = lane&15, k = quad*8 + j
    short8 Ah[4][2], Al[4][2];
    #pragma unroll
    for (int lsub = 0; lsub < 4; ++lsub) {
        int lrow = lblock + w * 64 + lsub * 16 + l16;
        float qm = qmask[n * L_ + lrow];
        const float* qp = Q + (((size_t)n * L_ + lrow) * H_ + h) * D_ + quad * 8;
        #pragma unroll
        for (int ks = 0; ks < 2; ++ks) {
            float4 v0 = *(const float4*)(qp + ks * 32);
            float4 v1 = *(const float4*)(qp + ks * 32 + 4);
            float fv[8];
            fv[0] = feat(v0.x) * qm; fv[1] = feat(v0.y) * qm;
            fv[2] = feat(v0.z) * qm; fv[3] = feat(v0.w) * qm;
            fv[4] = feat(v1.x) * qm; fv[5] = feat(v1.y) * qm;
            fv[6] = feat(v1.z) * qm; fv[7] = feat(v1.w) * qm;
            short8 hi, lo;
            #pragma unroll
            for (int j = 0; j < 8; ++j) {
                short hb = f2bf(fv[j]);
                hi[j] = hb;
                lo[j] = f2bf(fv[j] - bf2f(hb));
            }
            Ah[lsub][ks] = hi;
            Al[lsub][ks] = lo;
        }
    }

    // B-frag LDS byte offsets: row = ssub*16 + l16; 16B slot c of the row is
    // stored at slot c ^ (row&7); the two K-halves live at slots quad, quad+4.
    int boff[4][2];
    #pragma unroll
    for (int ssub = 0; ssub < 4; ++ssub) {
        int row = ssub * 16 + l16;
        int rx = l16 & 7;
        boff[ssub][0] = row * 128 + ((quad ^ rx) << 4);
        boff[ssub][1] = row * 128 + (((quad + 4) ^ rx) << 4);
    }

    float rmax[4][4];
    #pragma unroll
    for (int i = 0; i < 4; ++i)
        #pragma unroll
        for (int r = 0; r < 4; ++r) rmax[i][r] = 0.f;   // dots >= 0

    __syncthreads();   // drains stage(0) vmcnt + barrier

    const int tiles = S_ / SSPLIT / BS;    // 8
    for (int tile = 0; tile < tiles; ++tile) {
        int db = tile & 1;
        if (tile + 1 < tiles) stage(tile + 1, db ^ 1);   // prefetch next tile
        const char* hp = lds[db];
        const char* lp = lds[db] + 8192;
        #pragma unroll
        for (int ssub = 0; ssub < 4; ++ssub) {
            // B-frag layout: s-row = lane&15, k = quad*8 + j
            short8 Bh0 = *(const short8*)(hp + boff[ssub][0]);
            short8 Bh1 = *(const short8*)(hp + boff[ssub][1]);
            short8 Bl0 = *(const short8*)(lp + boff[ssub][0]);
            short8 Bl1 = *(const short8*)(lp + boff[ssub][1]);
            #pragma unroll
            for (int lsub = 0; lsub < 4; ++lsub) {
                floatx4 acc = {0.f, 0.f, 0.f, 0.f};
                acc = __builtin_amdgcn_mfma_f32_16x16x32_bf16(Ah[lsub][0], Bh0, acc, 0, 0, 0);
                acc = __builtin_amdgcn_mfma_f32_16x16x32_bf16(Ah[lsub][1], Bh1, acc, 0, 0, 0);
                acc = __builtin_amdgcn_mfma_f32_16x16x32_bf16(Ah[lsub][0], Bl0, acc, 0, 0, 0);
                acc = __builtin_amdgcn_mfma_f32_16x16x32_bf16(Ah[lsub][1], Bl1, acc, 0, 0, 0);
                acc = __builtin_amdgcn_mfma_f32_16x16x32_bf16(Al[lsub][0], Bh0, acc, 0, 0, 0);
                acc = __builtin_amdgcn_mfma_f32_16x16x32_bf16(Al[lsub][1], Bh1, acc, 0, 0, 0);
                #pragma unroll
                for (int r = 0; r < 4; ++r)
                    rmax[lsub][r] = fmaxf(rmax[lsub][r], acc[r]);
            }
        }
        __syncthreads();   // reads done + prefetched loads landed
    }

    // ---- epilogue: reduce rowmax across the 16 column-lanes, plain store ----
    // C/D layout: col(s) = lane&15, row(l) = quad*4 + r
    #pragma unroll
    for (int lsub = 0; lsub < 4; ++lsub)
        #pragma unroll
        for (int r = 0; r < 4; ++r) {
            float m = rmax[lsub][r];
            m = fmaxf(m, __shfl_xor(m, 1, 64));
            m = fmaxf(m, __shfl_xor(m, 2, 64));
            m = fmaxf(m, __shfl_xor(m, 4, 64));
            m = fmaxf(m, __shfl_xor(m, 8, 64));
            if (l16 == 0) {
                int l = lblock + w * 64 + lsub * 16 + quad * 4 + r;
                rmax_part[((size_t)(z * 16 + nh)) * L_ + l] = m;
            }
        }
}

// -------------------------------------------------------------------------
// finalize: float4 per thread; 16-lane row reduction for the mean-dot;
// max over the 4 z rowmax partials; gate; masked output.
// -------------------------------------------------------------------------
__global__ __launch_bounds__(256) void finalize_kernel(
        const float* __restrict__ Q, const float* __restrict__ qmask,
        const float* __restrict__ Ksum, const float* __restrict__ rmax_part,
        const float* __restrict__ W, const float* __restrict__ b,
        float* __restrict__ out) {
    int t = threadIdx.x;
    int fid = blockIdx.x * 256 + t;        // float4 index
    int wid = fid >> 4;                    // (n,l,h) row id
    int sub = fid & 15;                    // 16B chunk within the 64-d row
    int n = wid / (L_ * H_);
    int lh = wid % (L_ * H_);
    int l = lh / H_, h = lh % H_;
    int nh = n * H_ + h;

    float4 q4 = ((const float4*)Q)[fid];
    float qm = qmask[n * L_ + l];
    float4 ks4 = ((const float4*)(Ksum + nh * 64))[sub];
    float p = feat(q4.x) * ks4.x + feat(q4.y) * ks4.y
            + feat(q4.z) * ks4.z + feat(q4.w) * ks4.w;
    p *= qm;
    p += __shfl_xor(p, 1, 64);
    p += __shfl_xor(p, 2, 64);
    p += __shfl_xor(p, 4, 64);
    p += __shfl_xor(p, 8, 64);             // sum across the row's 16 lanes
    float mean = p * (1.0f / S_);
    float mx = fmaxf(
        fmaxf(rmax_part[((size_t)(0 * 16 + nh)) * L_ + l],
              rmax_part[((size_t)(1 * 16 + nh)) * L_ + l]),
        fmaxf(rmax_part[((size_t)(2 * 16 + nh)) * L_ + l],
              rmax_part[((size_t)(3 * 16 + nh)) * L_ + l]));
    float zz = W[0] * mean + W[1] * mx + b[0];
    float g = 1.0f / (1.0f + __expf(-zz));
    float4 o;
    o.x = q4.x * qm * g; o.y = q4.y * qm * g;
    o.z = q4.z * qm * g; o.w = q4.w * qm * g;
    ((float4*)out)[fid] = o;
}

extern "C" void kernel_launch(void* const* d_in, const int* in_sizes, int n_in,
                              void* d_out, int out_size, void* d_ws, size_t ws_size,
                              hipStream_t stream) {
    const float* Q      = (const float*)d_in[0];
    const float* K      = (const float*)d_in[1];
    // d_in[2] = values: masked in reference but unused downstream
    const float* qmask  = (const float*)d_in[3];
    const float* kvmask = (const float*)d_in[4];
    const float* W      = (const float*)d_in[5];
    const float* b      = (const float*)d_in[6];
    float* out = (float*)d_out;

    // workspace layout (floats), everything written before read, no init:
    float* Ksum      = (float*)d_ws;                     // 1024
    float* Kpart     = Ksum + 1024;                      // 16*32*64 = 32768
    float* rmax_part = Kpart + 32768;                    // 4*16*2048 = 131072
    short* Khi       = (short*)(rmax_part + 131072);     // 4 MB (16B-aligned)
    short* Klo       = Khi + (size_t)N_ * H_ * S_ * D_;  // 4 MB

    featk_kernel<<<dim3(N_ * H_, S_ / 64), 256, 0, stream>>>(K, kvmask, Khi, Klo, Kpart);
    rowmax_mfma<<<dim3(L_ / BLK_L, N_ * H_, SSPLIT), 256, 0, stream>>>(
        Q, Khi, Klo, qmask, Kpart, Ksum, rmax_part);
    finalize_kernel<<<dim3((N_ * L_ * H_ * D_ / 4) / 256), 256, 0, stream>>>(
        Q, qmask, Ksum, rmax_part, W, b, out);
}